// Round 1
// baseline (516.400 us; speedup 1.0000x reference)
//
#include <hip/hip_runtime.h>
#include <hip/hip_bf16.h>
#include <cstdint>
#include <cstddef>

using bf16    = __bf16;
using bf16x4  = __attribute__((ext_vector_type(4))) __bf16;
using bf16x8  = __attribute__((ext_vector_type(8))) __bf16;
using floatx4 = __attribute__((ext_vector_type(4))) float;

__device__ __forceinline__ void async_cp16(const bf16* g, bf16* l) {
    // gfx950: direct global->LDS DMA, 16B per lane, LDS dest = wave-uniform base + lane*16
    __builtin_amdgcn_global_load_lds(
        (__attribute__((address_space(1))) void*)const_cast<bf16*>(g),
        (__attribute__((address_space(3))) void*)l,
        16, 0, 0);
}

// ---------------------------------------------------------------------------
// prep: xv = bf16(x*tmv + (1-tmv)*xx), xr = bf16(x*tmr + (1-tmr)*xx)
// float4-vectorized; c index wraps every C elements.
// ---------------------------------------------------------------------------
__global__ __launch_bounds__(256) void prep_kernel(
    const float* __restrict__ x, const float* __restrict__ tmv,
    const float* __restrict__ tmr, const float* __restrict__ xxp,
    bf16* __restrict__ xv, bf16* __restrict__ xr, int nvec, int cvec_mask) {
    int vid = blockIdx.x * blockDim.x + threadIdx.x;
    if (vid >= nvec) return;
    int c = (vid & cvec_mask) * 4;
    float4 xi = ((const float4*)x)[vid];
    float4 mv = *(const float4*)&tmv[c];
    float4 mr = *(const float4*)&tmr[c];
    float4 x0 = *(const float4*)&xxp[c];
    float xa[4]  = {xi.x, xi.y, xi.z, xi.w};
    float mva[4] = {mv.x, mv.y, mv.z, mv.w};
    float mra[4] = {mr.x, mr.y, mr.z, mr.w};
    float x0a[4] = {x0.x, x0.y, x0.z, x0.w};
    bf16x4 ov, og;
#pragma unroll
    for (int u = 0; u < 4; ++u) {
        ov[u] = (bf16)(xa[u] * mva[u] + (1.0f - mva[u]) * x0a[u]);
        og[u] = (bf16)(xa[u] * mra[u] + (1.0f - mra[u]) * x0a[u]);
    }
    *(bf16x4*)&xv[(size_t)vid * 4] = ov;
    *(bf16x4*)&xr[(size_t)vid * 4] = og;
}

__global__ __launch_bounds__(256) void cvt_bf16_kernel(
    const float* __restrict__ in, bf16* __restrict__ out, int nvec) {
    int vid = blockIdx.x * blockDim.x + threadIdx.x;
    if (vid >= nvec) return;
    float4 f = ((const float4*)in)[vid];
    bf16x4 o;
    o[0] = (bf16)f.x; o[1] = (bf16)f.y; o[2] = (bf16)f.z; o[3] = (bf16)f.w;
    *(bf16x4*)&out[(size_t)vid * 4] = o;
}

// ---------------------------------------------------------------------------
// NT GEMM: C[m][n] = sum_k A[m][k] * Bw[n][k]; A: MxK row-major, Bw: NxK row-major.
// 128x128 tile, BK=32, 256 threads (4 waves, 2x2 of 64x64), 16x16x32 bf16 MFMA.
// EPI: 0 = store bf16; 1 = store bf16(sigmoid(acc)*Vaux); 2 = store fp32.
// ---------------------------------------------------------------------------
template <int EPI>
__global__ __launch_bounds__(256) void gemm_bt(
    const bf16* __restrict__ A, const bf16* __restrict__ Bw,
    const bf16* __restrict__ Vaux, bf16* __restrict__ Ob,
    float* __restrict__ Of, int M, int N, int K) {
    __shared__ __align__(16) bf16 sA[128 * 32];
    __shared__ __align__(16) bf16 sB[128 * 32];

    const int tid  = threadIdx.x;
    const int wave = tid >> 6;
    const int lane = tid & 63;
    const int quad = lane >> 4;
    const int l16  = lane & 15;
    const int m0   = blockIdx.y * 128;
    const int n0   = blockIdx.x * 128;
    const int wm   = (wave >> 1) * 64;  // wave's row offset in tile
    const int wn   = (wave & 1) * 64;   // wave's col offset in tile

    floatx4 acc[4][4];
#pragma unroll
    for (int i = 0; i < 4; ++i)
#pragma unroll
        for (int j = 0; j < 4; ++j) acc[i][j] = (floatx4){0.f, 0.f, 0.f, 0.f};

    // staging: 512 chunks of 16B per tile (128 rows x 4 chunks); thread t -> chunks t, t+256
    const int row0 = tid >> 2;          // 0..63
    const int col0 = (tid & 3) * 8;     // element offset within the 32-wide k-slab
    const bf16* gA0 = A + (size_t)(m0 + row0) * K + col0;
    const bf16* gA1 = gA0 + (size_t)64 * K;
    const bf16* gB0 = Bw + (size_t)(n0 + row0) * K + col0;
    const bf16* gB1 = gB0 + (size_t)64 * K;
    bf16* lA0 = &sA[wave * 512];
    bf16* lA1 = &sA[2048 + wave * 512];
    bf16* lB0 = &sB[wave * 512];
    bf16* lB1 = &sB[2048 + wave * 512];

    const int kIters = K >> 5;
    for (int it = 0; it < kIters; ++it) {
        __syncthreads();  // previous iter's LDS readers done
        async_cp16(gA0, lA0);
        async_cp16(gA1, lA1);
        async_cp16(gB0, lB0);
        async_cp16(gB1, lB1);
        gA0 += 32; gA1 += 32; gB0 += 32; gB1 += 32;
        __syncthreads();  // staging drained (vmcnt(0) before barrier)

        bf16x8 af[4], bfg[4];
#pragma unroll
        for (int i = 0; i < 4; ++i)
            af[i] = *(const bf16x8*)&sA[(wm + i * 16 + l16) * 32 + quad * 8];
#pragma unroll
        for (int j = 0; j < 4; ++j)
            bfg[j] = *(const bf16x8*)&sB[(wn + j * 16 + l16) * 32 + quad * 8];
#pragma unroll
        for (int i = 0; i < 4; ++i)
#pragma unroll
            for (int j = 0; j < 4; ++j)
                acc[i][j] = __builtin_amdgcn_mfma_f32_16x16x32_bf16(
                    af[i], bfg[j], acc[i][j], 0, 0, 0);
    }

    // epilogue: C/D layout (16x16x32): col = lane&15, row = quad*4 + reg
    const int rbase = quad * 4;
#pragma unroll
    for (int i = 0; i < 4; ++i) {
#pragma unroll
        for (int j = 0; j < 4; ++j) {
            const int col = n0 + wn + j * 16 + l16;
#pragma unroll
            for (int r = 0; r < 4; ++r) {
                const int row = m0 + wm + i * 16 + rbase + r;
                const size_t o = (size_t)row * N + col;
                const float va = acc[i][j][r];
                if (EPI == 0) {
                    Ob[o] = (bf16)va;
                } else if (EPI == 1) {
                    const float vv = (float)Vaux[o];
                    const float sg = 1.0f / (1.0f + __expf(-va));
                    Ob[o] = (bf16)(sg * vv);
                } else {
                    Of[o] = va;
                }
            }
        }
    }
}

extern "C" void kernel_launch(void* const* d_in, const int* in_sizes, int n_in,
                              void* d_out, int out_size, void* d_ws, size_t ws_size,
                              hipStream_t stream) {
    // inputs: 0:x 1:time_first 2:tmk 3:tmv 4:tmr 5:xx 6:aa 7:bb 8:pp
    //         9:w_key 10:w_value 11:w_rec 12:w_out
    const int C = in_sizes[1];              // 2048
    const int M = in_sizes[0] / C;          // B*T = 8192
    const size_t MC = (size_t)M * C;
    const size_t CC = (size_t)C * C;

    const float* x   = (const float*)d_in[0];
    const float* tmv = (const float*)d_in[3];
    const float* tmr = (const float*)d_in[4];
    const float* xxp = (const float*)d_in[5];
    const float* wv  = (const float*)d_in[10];
    const float* wr  = (const float*)d_in[11];
    const float* wo  = (const float*)d_in[12];
    float* out = (float*)d_out;

    uint8_t* ws = (uint8_t*)d_ws;
    // layout (bf16): xv[MC], xr[MC], v[MC], wv[CC], wr[CC], wo[CC]
    const size_t need_full = MC * 6 + CC * 6;
    bf16* xv;
    bf16* xr;
    bf16* vbuf;
    bf16* wvb;
    bf16* wrb;
    bf16* wob;
    if (ws_size >= need_full) {
        xv   = (bf16*)(ws);
        xr   = (bf16*)(ws + MC * 2);
        vbuf = (bf16*)(ws + MC * 4);
        wvb  = (bf16*)(ws + MC * 6);
        wrb  = (bf16*)(ws + MC * 6 + CC * 2);
        wob  = (bf16*)(ws + MC * 6 + CC * 4);
    } else {
        // fallback: park v (bf16) in the front half of d_out (fp32, 2x the bytes);
        // it is fully consumed by GEMM_r before GEMM_out overwrites d_out.
        xv   = (bf16*)(ws);
        xr   = (bf16*)(ws + MC * 2);
        vbuf = (bf16*)d_out;
        wvb  = (bf16*)(ws + MC * 4);
        wrb  = (bf16*)(ws + MC * 4 + CC * 2);
        wob  = (bf16*)(ws + MC * 4 + CC * 4);
    }
    bf16* rwkv = xv;  // xv is dead after GEMM_v

    const int nvecX = (int)(MC / 4);
    prep_kernel<<<(nvecX + 255) / 256, 256, 0, stream>>>(x, tmv, tmr, xxp, xv, xr,
                                                         nvecX, C / 4 - 1);
    const int nvecW = (int)(CC / 4);
    cvt_bf16_kernel<<<(nvecW + 255) / 256, 256, 0, stream>>>(wv, wvb, nvecW);
    cvt_bf16_kernel<<<(nvecW + 255) / 256, 256, 0, stream>>>(wr, wrb, nvecW);
    cvt_bf16_kernel<<<(nvecW + 255) / 256, 256, 0, stream>>>(wo, wob, nvecW);

    dim3 grid(C / 128, M / 128);  // (16, 64)
    // v = xv @ Wv^T            (store bf16)
    gemm_bt<0><<<grid, 256, 0, stream>>>(xv, wvb, nullptr, vbuf, nullptr, M, C, C);
    // rwkv = sigmoid(xr @ Wr^T) * v   (store bf16; wkv == v, see analysis)
    gemm_bt<1><<<grid, 256, 0, stream>>>(xr, wrb, vbuf, rwkv, nullptr, M, C, C);
    // out = rwkv @ Wo^T        (store fp32)
    gemm_bt<2><<<grid, 256, 0, stream>>>(rwkv, wob, nullptr, nullptr, out, M, C, C);
}